// Round 1
// baseline (22062.180 us; speedup 1.0000x reference)
//
#include <hip/hip_runtime.h>
#include <hip/hip_cooperative_groups.h>

namespace cg = cooperative_groups;

#define B_   512
#define T_   512
#define I_   64
#define R_   1024
#define O_   64
#define KTOT 1088  // R_ + I_ packed k-dimension of Wt

typedef __attribute__((ext_vector_type(8))) short short8;   // 8 bf16 (4 VGPR)
typedef __attribute__((ext_vector_type(4))) float float4v;  // MFMA acc

__device__ inline unsigned short f2bf(float x) {
  union { float f; unsigned u; } v; v.f = x;
  unsigned r = v.u + 0x7FFFu + ((v.u >> 16) & 1u);  // RNE
  return (unsigned short)(r >> 16);
}
__device__ inline float bf2f(unsigned short h) {
  union { unsigned u; float f; } v; v.u = ((unsigned)h) << 16;
  return v.f;
}

// Pack Wt[n][k] (bf16): k in [0,1024) = W_res[k][n]; k in [1024,1088) = W_in[k-1024][n].
// 32x32 LDS tile transpose; grid = (32 n-tiles, 34 k-tiles), block = 256.
__global__ void esn_prep_wt(const float* __restrict__ Wres, const float* __restrict__ Win,
                            unsigned short* __restrict__ Wt) {
  __shared__ float tile[32][33];
  int nt = blockIdx.x, kt = blockIdx.y;
  int tx = threadIdx.x & 31;   // inner coalesced index
  int ty = threadIdx.x >> 5;   // 0..7
  int k0 = kt * 32, n0 = nt * 32;
  #pragma unroll
  for (int s = 0; s < 4; ++s) {
    int k = k0 + ty + 8 * s;
    int n = n0 + tx;
    float v = (k < R_) ? Wres[(size_t)k * R_ + n] : Win[(size_t)(k - R_) * R_ + n];
    tile[ty + 8 * s][tx] = v;
  }
  __syncthreads();
  #pragma unroll
  for (int s = 0; s < 4; ++s) {
    int n = n0 + ty + 8 * s;
    int k = k0 + tx;
    Wt[(size_t)n * KTOT + k] = f2bf(tile[tx][ty + 8 * s]);
  }
}

// Persistent cooperative recurrence kernel.
// Grid 256 blocks x 512 threads (8 waves). Block (i = bid&15 row-group, j = bid>>4 col-group)
// owns output tile state[i*32 .. +32)[j*64 .. +64). Wave w: mw=w&1 (16-row block),
// nw=w>>1 (16-col block). MFMA 16x16x32 bf16, f32 acc; f32 master state in s_local.
__global__ __launch_bounds__(512) void esn_recur(
    const float* __restrict__ input, const unsigned short* __restrict__ Wt,
    unsigned short* __restrict__ sbuf0, unsigned short* __restrict__ sbuf1) {
  cg::grid_group grid = cg::this_grid();
  int bid = blockIdx.x;
  int gi = bid & 15;   // row group -> bid%8 keeps a row-group's 16 blocks on one XCD
  int gj = bid >> 4;   // col group
  int tid = threadIdx.x;
  int lane = tid & 63;
  int w = tid >> 6;
  int mw = w & 1;
  int nw = w >> 1;     // 0..3
  int row_a = lane & 15;      // A-frag row / B,C col index
  int kgrp  = lane >> 4;      // 0..3: A/B k-block, C row-block

  int b_frag = gi * 32 + mw * 16 + row_a;          // state row this lane loads (A)
  int n_frag = gj * 64 + nw * 16 + row_a;          // W col this lane loads (B) == C col
  int c_row  = gi * 32 + mw * 16 + kgrp * 4;       // C rows c_row .. c_row+3

  const unsigned short* wt_row = Wt + (size_t)n_frag * KTOT;
  const short8* brow = (const short8*)(wt_row + kgrp * 8);        // index kk*4 -> k=kk*32+kgrp*8
  float s_local[4] = {0.f, 0.f, 0.f, 0.f};

  for (int t = 0; t < T_; ++t) {
    const unsigned short* sin = (t & 1) ? sbuf1 : sbuf0;
    unsigned short* sout      = (t & 1) ? sbuf0 : sbuf1;
    float4v acc = {0.f, 0.f, 0.f, 0.f};

    if (t > 0) {
      const short8* arow = (const short8*)(sin + (size_t)b_frag * R_ + kgrp * 8);
      #pragma unroll 8
      for (int kk = 0; kk < 32; ++kk) {
        short8 a = arow[kk * 4];
        short8 b = brow[kk * 4];
        acc = __builtin_amdgcn_mfma_f32_16x16x32_bf16(a, b, acc, 0, 0, 0);
      }
    }
    // fused u_t contribution: k = 1024 + i
    {
      const float* irow = input + ((size_t)b_frag * T_ + t) * I_;
      #pragma unroll
      for (int kk = 0; kk < 2; ++kk) {
        int ib = kk * 32 + kgrp * 8;
        short8 a;
        #pragma unroll
        for (int jj = 0; jj < 8; ++jj) a[jj] = (short)f2bf(irow[ib + jj]);
        short8 b = *(const short8*)(wt_row + R_ + ib);
        acc = __builtin_amdgcn_mfma_f32_16x16x32_bf16(a, b, acc, 0, 0, 0);
      }
    }
    // leak + tanh + bf16 broadcast write (C/D: col = lane&15, row = kgrp*4 + r)
    #pragma unroll
    for (int r = 0; r < 4; ++r) {
      float ns = 0.5f * s_local[r] + 0.5f * tanhf(acc[r]);
      s_local[r] = ns;
      sout[(size_t)(c_row + r) * R_ + n_frag] = f2bf(ns);
    }
    grid.sync();
  }
}

// out[b][o] = sum_r state_bf16[b][r] * W_out[r][o], f32 accumulate.
__global__ void esn_out_gemm(const unsigned short* __restrict__ state,
                             const float* __restrict__ Wout, float* __restrict__ out) {
  int b = blockIdx.x;
  int o = threadIdx.x;  // 0..63
  const unsigned short* srow = state + (size_t)b * R_;
  float acc = 0.f;
  #pragma unroll 8
  for (int r = 0; r < R_; ++r) acc += bf2f(srow[r]) * Wout[r * O_ + o];
  out[b * O_ + o] = acc;
}

extern "C" void kernel_launch(void* const* d_in, const int* in_sizes, int n_in,
                              void* d_out, int out_size, void* d_ws, size_t ws_size,
                              hipStream_t stream) {
  const float* input = (const float*)d_in[0];
  const float* Wres  = (const float*)d_in[1];
  const float* Win   = (const float*)d_in[2];
  const float* Wout  = (const float*)d_in[3];
  float* out = (float*)d_out;

  // ws layout: Wt (1024*1088*2 = 2,228,224 B) | s0 (1 MB) | s1 (1 MB)  => ~4.2 MB total
  char* ws = (char*)d_ws;
  unsigned short* Wt = (unsigned short*)ws;
  unsigned short* s0 = (unsigned short*)(ws + 2228224);
  unsigned short* s1 = (unsigned short*)(ws + 2228224 + 1048576);

  esn_prep_wt<<<dim3(32, 34), 256, 0, stream>>>(Wres, Win, Wt);

  void* args[] = { (void*)&input, (void*)&Wt, (void*)&s0, (void*)&s1 };
  hipLaunchCooperativeKernel((void*)esn_recur, dim3(256), dim3(512), args, 0, stream);

  // after t=511 (odd), final state is in s0
  esn_out_gemm<<<512, 64, 0, stream>>>(s0, Wout, out);
}

// Round 3
// 9109.329 us; speedup vs baseline: 2.4219x; 2.4219x over previous
//
#include <hip/hip_runtime.h>

#define B_   512
#define T_   512
#define I_   64
#define R_   1024
#define O_   64
#define KK_  34      // k-blocks of 32: 1024 state + 64 input = 1088
#define NT_STRIDE 17408   // shorts per 16-col n-tile: 34*4*16*8

typedef __attribute__((ext_vector_type(8))) short short8;   // 8 bf16
typedef __attribute__((ext_vector_type(4))) float float4v;  // MFMA acc

__device__ inline unsigned short f2bf(float x) {
  union { float f; unsigned u; } v; v.f = x;
  unsigned r = v.u + 0x7FFFu + ((v.u >> 16) & 1u);  // RNE
  return (unsigned short)(r >> 16);
}
__device__ inline float bf2f(unsigned short h) {
  union { unsigned u; float f; } v; v.u = ((unsigned)h) << 16;
  return v.f;
}
// fast tanh: 1 - 2/(1+e^{2x}); exact at 0, saturates correctly at +/-inf (no NaN)
__device__ inline float ftanh(float x) {
  float e = __expf(2.0f * x);
  return 1.0f - 2.0f / (e + 1.0f);
}

// frag-contiguous index for element (k, n) of the packed weight Wt2:
//   ntile=n>>4, kk=k>>5, kg=(k>>3)&3, nl=n&15, j=k&7
__device__ inline size_t wt2_idx(int k, int n) {
  return ((((size_t)(n >> 4) * KK_ + (k >> 5)) * 4 + ((k >> 3) & 3)) * 16 + (n & 15)) * 8 + (k & 7);
}

// Pack W (k<1024: W_res[k][n]; k>=1024: W_in[k-1024][n]) -> bf16 frag-contiguous.
// grid (32 n-tiles of 32, 34 k-tiles of 32), block 256. LDS tile transpose for coalesced reads.
__global__ void esn_prep_wt(const float* __restrict__ Wres, const float* __restrict__ Win,
                            unsigned short* __restrict__ Wt2) {
  __shared__ float tile[32][33];
  int nt = blockIdx.x, kt = blockIdx.y;
  int tx = threadIdx.x & 31;
  int ty = threadIdx.x >> 5;
  int k0 = kt * 32, n0 = nt * 32;
  #pragma unroll
  for (int s = 0; s < 4; ++s) {
    int k = k0 + ty + 8 * s;
    int n = n0 + tx;
    float v = (k < R_) ? Wres[(size_t)k * R_ + n] : Win[(size_t)(k - R_) * R_ + n];
    tile[ty + 8 * s][tx] = v;
  }
  __syncthreads();
  #pragma unroll
  for (int s = 0; s < 4; ++s) {
    int n = n0 + ty + 8 * s;
    int k = k0 + tx;
    Wt2[wt2_idx(k, n)] = f2bf(tile[tx][ty + 8 * s]);
  }
}

// Zero-communication recurrence: 32 blocks x 1024 threads (16 waves).
// Block g owns batch rows g*16..+16; full 1024-wide state in LDS (bf16, frag layout)
// + f32 master in registers. Wave w computes output cols [w*64, w*64+64).
// A-frag (state) layout in LDS: idx = ((kk*4+kg)*16 + m)*8 + j  for k=kk*32+kg*8+j.
__global__ __launch_bounds__(1024, 4) void esn_recur(
    const float* __restrict__ input, const unsigned short* __restrict__ Wt2,
    const float* __restrict__ Wout, float* __restrict__ out) {
  __shared__ unsigned short aLds[KK_ * 4 * 16 * 8];  // 17408 shorts = 34816 B

  int tid  = threadIdx.x;
  int lane = tid & 63;
  int w    = tid >> 6;        // wave 0..15 -> cols w*64..+64
  int nl   = lane & 15;       // A row (batch m) for A-frag; B/C col within tile
  int kgrp = lane >> 4;       // k-subblock 0..3; C row-block
  int bg0  = blockIdx.x * 16; // first batch row of this block

  // u-staging role: one element per thread
  int m_u = tid >> 6;         // 0..15
  int i_u = tid & 63;         // 0..63
  int k_u = R_ + i_u;
  int idx_u = (((k_u >> 5) * 4 + ((k_u >> 3) & 3)) * 16 + m_u) * 8 + (k_u & 7);
  const float* inp_u = input + ((size_t)(bg0 + m_u) * T_) * I_ + i_u;

  // zero state region (k < 1024 -> first 16384 shorts = 8192 ints)
  int* zp = (int*)aLds;
  #pragma unroll
  for (int s = 0; s < 8; ++s) zp[tid + 1024 * s] = 0;
  // stage u_0
  aLds[idx_u] = f2bf(inp_u[0]);
  __syncthreads();

  // per-wave pointers
  const unsigned short* aBase = aLds + ((size_t)kgrp * 16 + nl) * 8;        // + kk*512
  const unsigned short* bBase = Wt2 + (size_t)(w * 4) * NT_STRIDE + kgrp * 128 + nl * 8;

  float s_local[4][4];  // [nn][r] f32 master state: col = w*64+nn*16+nl, row m = kgrp*4+r
  #pragma unroll
  for (int nn = 0; nn < 4; ++nn)
    #pragma unroll
    for (int r = 0; r < 4; ++r) s_local[nn][r] = 0.f;

  for (int t = 0; t < T_; ++t) {
    // prefetch next step's input element (hides HBM latency under MFMAs)
    float un = (t < T_ - 1) ? inp_u[(size_t)(t + 1) * I_] : 0.f;

    float4v acc[4];
    #pragma unroll
    for (int nn = 0; nn < 4; ++nn) acc[nn] = (float4v){0.f, 0.f, 0.f, 0.f};

    #pragma unroll 2
    for (int kk = 0; kk < KK_; ++kk) {
      short8 a = *(const short8*)(aBase + kk * 512);
      #pragma unroll
      for (int nn = 0; nn < 4; ++nn) {
        short8 b = *(const short8*)(bBase + (size_t)nn * NT_STRIDE + kk * 512);
        acc[nn] = __builtin_amdgcn_mfma_f32_16x16x32_bf16(a, b, acc[nn], 0, 0, 0);
      }
    }

    __syncthreads();  // all reads of step-t state done

    // leak + tanh, update master state, publish bf16 state_{t+1} + u_{t+1}
    #pragma unroll
    for (int nn = 0; nn < 4; ++nn) {
      int n_g = w * 64 + nn * 16 + nl;
      int base = (((n_g >> 5) * 4 + ((n_g >> 3) & 3)) * 16) * 8 + (n_g & 7);
      #pragma unroll
      for (int r = 0; r < 4; ++r) {
        int m = kgrp * 4 + r;
        float ns = 0.5f * s_local[nn][r] + 0.5f * ftanh(acc[nn][r]);
        s_local[nn][r] = ns;
        aLds[base + m * 8] = f2bf(ns);
      }
    }
    aLds[idx_u] = f2bf(un);
    __syncthreads();
  }

  // fused output projection from bf16 state in LDS:
  // thread (mo = tid>>6, o = tid&63): out[bg0+mo][o] = sum_r state[mo][r] * Wout[r][o]
  int o = tid & 63, mo = tid >> 6;
  const float* wo = Wout + o;
  float accO = 0.f;
  #pragma unroll 8
  for (int r = 0; r < R_; ++r) {
    int idx = (((r >> 5) * 4 + ((r >> 3) & 3)) * 16 + mo) * 8 + (r & 7);
    accO += bf2f(aLds[idx]) * wo[(size_t)r * O_];
  }
  out[(size_t)(bg0 + mo) * O_ + o] = accO;
}

extern "C" void kernel_launch(void* const* d_in, const int* in_sizes, int n_in,
                              void* d_out, int out_size, void* d_ws, size_t ws_size,
                              hipStream_t stream) {
  const float* input = (const float*)d_in[0];
  const float* Wres  = (const float*)d_in[1];
  const float* Win   = (const float*)d_in[2];
  const float* Wout  = (const float*)d_in[3];
  float* out = (float*)d_out;

  unsigned short* Wt2 = (unsigned short*)d_ws;  // 1088*1024*2 = 2,228,224 B

  esn_prep_wt<<<dim3(32, 34), 256, 0, stream>>>(Wres, Win, Wt2);
  esn_recur<<<32, 1024, 0, stream>>>(input, Wt2, Wout, out);
}